// Round 19
// baseline (1126.635 us; speedup 1.0000x reference)
//
#include <hip/hip_runtime.h>
#include <hip/hip_bf16.h>

#define Nn 16384
#define Dd 256
#define L2E 1.4426950408889634f
#define LN2 0.6931471805599453f

typedef __attribute__((ext_vector_type(8))) int int8v;
typedef __attribute__((ext_vector_type(16))) float f32x16;
typedef __attribute__((ext_vector_type(2))) float f32x2;

__device__ inline void gload_lds16(const void* g, void* l) {
    __builtin_amdgcn_global_load_lds(
        (const __attribute__((address_space(1))) void*)g,
        (__attribute__((address_space(3))) void*)l, 16, 0, 0);
}

// fp32 -> fp8 e4m3 (HW RNE). A pre-scaled by log2e: epilogue softplus works in
// exp2/log2 domain with no per-element muls.
__global__ __launch_bounds__(256) void cvt_kernel(
        const float4* __restrict__ a, const float4* __restrict__ b,
        int2* __restrict__ oa, int2* __restrict__ ob) {
    int i = blockIdx.x * 256 + threadIdx.x;
    float4 a0 = a[2 * i], a1 = a[2 * i + 1];
    float4 b0 = b[2 * i], b1 = b[2 * i + 1];
    int alo = __builtin_amdgcn_cvt_pk_fp8_f32(a0.x * L2E, a0.y * L2E, 0, false);
    alo     = __builtin_amdgcn_cvt_pk_fp8_f32(a0.z * L2E, a0.w * L2E, alo, true);
    int ahi = __builtin_amdgcn_cvt_pk_fp8_f32(a1.x * L2E, a1.y * L2E, 0, false);
    ahi     = __builtin_amdgcn_cvt_pk_fp8_f32(a1.z * L2E, a1.w * L2E, ahi, true);
    int blo = __builtin_amdgcn_cvt_pk_fp8_f32(b0.x, b0.y, 0, false);
    blo     = __builtin_amdgcn_cvt_pk_fp8_f32(b0.z, b0.w, blo, true);
    int bhi = __builtin_amdgcn_cvt_pk_fp8_f32(b1.x, b1.y, 0, false);
    bhi     = __builtin_amdgcn_cvt_pk_fp8_f32(b1.z, b1.w, bhi, true);
    oa[i] = make_int2(alo, ahi);
    ob[i] = make_int2(blo, bhi);
}

// 2x ds_read_b128 of one lane's 32 contiguous K-bytes from a [rows][256B]
// full-K LDS tile, XOR-deswizzled (16 chunks/row, chunk ^= row&15).
// Measured ZERO bank conflicts (R8-R18). LDS dest LINEAR (rule #21);
// swizzle lives on the global SOURCE side only.
__device__ inline int8v read_frag256(const unsigned char* base, int rr, int cb) {
    int x = rr & 15;
    int4 lo = *(const int4*)&base[rr * 256 + ((cb ^ x) * 16)];
    int4 hi = *(const int4*)&base[rr * 256 + (((cb + 1) ^ x) * 16)];
    int8v r;
    r[0] = lo.x; r[1] = lo.y; r[2] = lo.z; r[3] = lo.w;
    r[4] = hi.x; r[5] = hi.y; r[6] = hi.z; r[7] = hi.w;
    return r;
}

// Fused MX-fp8 GEMM (sim' = log2e * za.zb^T, unit e8m0 scales) + siglip loss.
// R18 (persistent-A pipelined-B, 256 thr = 1 wave/SIMD, 512-reg cap, no
// spill at VGPR=252) + SOFTWARE-PIPELINED EPILOGUE: two named acc
// generations accA/accB; panel t's MFMAs and panel t-1's epilogue share one
// barrier-delimited scheduling region, so the epilogue's VALU/trans issues
// in the MFMA pipe's idle issue slots (R18 profile: MFMA needs 17.4k cyc,
// epilogue+VALU ~30k run BEYOND it because 1 wave/SIMD serializes phases).
// Budget: 256 AGPR (2 gens) + ~130 arch < 512-reg cap at (256,1).
__global__ __launch_bounds__(256, 1) void siglip_kernel(
        const unsigned char* __restrict__ ga,   // za*log2e fp8 [16384][256]
        const unsigned char* __restrict__ gb,   // zb fp8 [16384][256]
        const float* __restrict__ bp,           // bias scalar
        float* __restrict__ out) {
    __shared__ unsigned char As[256 * 256];    // 64 KB, full-K A tile
    __shared__ unsigned char Bs0[128 * 256];   // 32 KB, B panel buffer 0
    __shared__ unsigned char Bs1[128 * 256];   // 32 KB, B panel buffer 1
    __shared__ float wsum[4];

    const int tid  = threadIdx.x;
    const int lane = tid & 63;
    const int wid  = tid >> 6;     // 0..3
    const int wm   = wid;          // 64-row slice of the 256-row tile
    const int l31  = lane & 31;
    const int h    = lane >> 5;

    // XCD-chunked bijective swizzle (grid 1024 = 8 XCD x 128); consecutive
    // nid share the A panel (same by) and sweep B -> per-XCD L2 locality.
    const int bid = blockIdx.x;
    const int nid = (bid & 7) * 128 + (bid >> 3);
    const int by  = nid >> 4;      // 0..63  M-tile (256 rows)
    const int bxs = nid & 15;      // 0..15  N-supertile (1024 cols)
    const size_t rowA0 = (size_t)by * 256;
    const int    rB0   = bxs * 1024;

    const float b2 = bp[0] * L2E;

    // ---- stage A once: 16 loads/thread; LDS dest linear, source swizzled ----
#pragma unroll
    for (int p = 0; p < 16; ++p) {
        int c = p * 256 + tid; int row = c >> 4;
        int scl = (c & 15) ^ (row & 15);
        gload_lds16(&ga[(rowA0 + row) * Dd + scl * 16], &As[c * 16]);
    }

#define STAGE_B(DST, T)                                                       \
    {                                                                         \
        _Pragma("unroll")                                                     \
        for (int p = 0; p < 8; ++p) {                                         \
            int c = p * 256 + tid; int row = c >> 4;                          \
            int scl = (c & 15) ^ (row & 15);                                  \
            gload_lds16(&gb[(size_t)(rB0 + (T) * 128 + row) * Dd + scl * 16], \
                        &(DST)[c * 16]);                                      \
        }                                                                     \
    }

    STAGE_B(Bs0, 0)
    STAGE_B(Bs1, 1)

    // outstanding: A(16)+B0(8)+B1(8)=32; wait to <=8 -> A and B0 landed.
    asm volatile("s_waitcnt vmcnt(8)" ::: "memory");
    __builtin_amdgcn_s_barrier();
    asm volatile("" ::: "memory");

    f32x2 sm = {0.f, 0.f}, se = {0.f, 0.f};
    float ld = 0.f;
    const int diagblk = (bxs == (by >> 2));
    const int dtile   = (by & 3);

    f32x16 accA[2][4], accB[2][4];

    // compute panel into ACC (init + 4 s-steps x {3 ds_reads-per-nf, 8 MFMA})
#define PANEL_COMPUTE(ACC, BBUF)                                              \
    {                                                                         \
        _Pragma("unroll")                                                     \
        for (int mf = 0; mf < 2; ++mf)                                        \
            _Pragma("unroll")                                                 \
            for (int nf = 0; nf < 4; ++nf)                                    \
                _Pragma("unroll")                                             \
                for (int q = 0; q < 16; ++q) (ACC)[mf][nf][q] = -b2;          \
        _Pragma("unroll")                                                     \
        for (int s = 0; s < 4; ++s) {                                         \
            int cb = s * 4 + h * 2;                                           \
            int8v aF0 = read_frag256(As, wm * 64 + l31, cb);                  \
            int8v aF1 = read_frag256(As, wm * 64 + 32 + l31, cb);             \
            _Pragma("unroll")                                                 \
            for (int nf = 0; nf < 4; ++nf) {                                  \
                int8v bF = read_frag256(BBUF, nf * 32 + l31, cb);             \
                (ACC)[0][nf] =                                                \
                    __builtin_amdgcn_mfma_scale_f32_32x32x64_f8f6f4(          \
                        aF0, bF, (ACC)[0][nf], 0, 0, 0,                       \
                        0x7F7F7F7F, 0, 0x7F7F7F7F);                           \
                (ACC)[1][nf] =                                                \
                    __builtin_amdgcn_mfma_scale_f32_32x32x64_f8f6f4(          \
                        aF1, bF, (ACC)[1][nf], 0, 0, 0,                       \
                        0x7F7F7F7F, 0, 0x7F7F7F7F);                           \
            }                                                                 \
        }                                                                     \
    }

    // epilogue of a finished panel TT (runs interleaved with next MFMAs):
    // loss/elem(nats) ~= ln2*m + 2^(y-2m), m=max(y,0) (y-2m == -|y|).
#define PANEL_EPILOGUE(ACC, TT)                                               \
    {                                                                         \
        _Pragma("unroll")                                                     \
        for (int mf = 0; mf < 2; ++mf)                                        \
            _Pragma("unroll")                                                 \
            for (int nf = 0; nf < 4; ++nf)                                    \
                _Pragma("unroll")                                             \
                for (int q = 0; q < 16; q += 2) {                             \
                    f32x2 yv = {(ACC)[mf][nf][q], (ACC)[mf][nf][q + 1]};      \
                    f32x2 mv = {fmaxf(yv[0], 0.f), fmaxf(yv[1], 0.f)};        \
                    f32x2 tv = yv - 2.f * mv;  /* = -|y|, v_pk_fma */         \
                    sm += mv;                                                 \
                    f32x2 ev = {__builtin_amdgcn_exp2f(tv[0]),                \
                                __builtin_amdgcn_exp2f(tv[1])};               \
                    se += ev;                                                 \
                }                                                             \
        if (diagblk && ((TT) >> 1) == dtile) {                                \
            _Pragma("unroll")                                                 \
            for (int mf = 0; mf < 2; ++mf)                                    \
                _Pragma("unroll")                                             \
                for (int nf = 0; nf < 4; ++nf)                                \
                    _Pragma("unroll")                                         \
                    for (int q = 0; q < 16; ++q) {                            \
                        int i_loc = wm * 64 + mf * 32 + (q & 3) +             \
                                    8 * (q >> 2) + 4 * h;                     \
                        int jg = (((TT) & 1) << 7) + nf * 32 + l31;           \
                        if (i_loc == jg) {                                    \
                            float y  = (ACC)[mf][nf][q];                      \
                            float u  = -(y + 2.f * b2);                       \
                            float ey = __builtin_amdgcn_exp2f(-fabsf(y));     \
                            float eu = __builtin_amdgcn_exp2f(-fabsf(u));     \
                            ld += (LN2 * fmaxf(u, 0.f) + eu) -                \
                                  (LN2 * fmaxf(y, 0.f) + ey);                 \
                        }                                                     \
                    }                                                         \
        }                                                                     \
    }

#define RDBAR  asm volatile("" ::: "memory"); __builtin_amdgcn_s_barrier();   \
               asm volatile("" ::: "memory");
#define WAIT8  asm volatile("s_waitcnt vmcnt(8)" ::: "memory");               \
               __builtin_amdgcn_s_barrier(); asm volatile("" ::: "memory");
#define WAIT0  asm volatile("s_waitcnt vmcnt(0)" ::: "memory");               \
               __builtin_amdgcn_s_barrier(); asm volatile("" ::: "memory");

    // ---- 8 panels; epilogue(t-1) fused into panel t's compute region ----
    PANEL_COMPUTE(accA, Bs0)                        // t=0
    RDBAR  STAGE_B(Bs0, 2)  WAIT8

    PANEL_COMPUTE(accB, Bs1)  PANEL_EPILOGUE(accA, 0)   // t=1
    RDBAR  STAGE_B(Bs1, 3)  WAIT8

    PANEL_COMPUTE(accA, Bs0)  PANEL_EPILOGUE(accB, 1)   // t=2
    RDBAR  STAGE_B(Bs0, 4)  WAIT8

    PANEL_COMPUTE(accB, Bs1)  PANEL_EPILOGUE(accA, 2)   // t=3
    RDBAR  STAGE_B(Bs1, 5)  WAIT8

    PANEL_COMPUTE(accA, Bs0)  PANEL_EPILOGUE(accB, 3)   // t=4
    RDBAR  STAGE_B(Bs0, 6)  WAIT8

    PANEL_COMPUTE(accB, Bs1)  PANEL_EPILOGUE(accA, 4)   // t=5
    RDBAR  STAGE_B(Bs1, 7)  WAIT8

    PANEL_COMPUTE(accA, Bs0)  PANEL_EPILOGUE(accB, 5)   // t=6
    RDBAR  WAIT0

    PANEL_COMPUTE(accB, Bs1)  PANEL_EPILOGUE(accA, 6)   // t=7
    PANEL_EPILOGUE(accB, 7)

    // v = ln2*Σm + Σe + diag
    float v = fmaf(LN2, sm[0] + sm[1], se[0] + se[1] + ld);

    // wave reduce then block reduce
#pragma unroll
    for (int off = 32; off; off >>= 1)
        v += __shfl_down(v, off);
    if (lane == 0) wsum[wid] = v;
    __syncthreads();
    if (tid == 0) {
        float t = wsum[0] + wsum[1] + wsum[2] + wsum[3];
        atomicAdd(out, t * (1.0f / ((float)Nn * (float)Nn)));
    }
#undef STAGE_B
#undef PANEL_COMPUTE
#undef PANEL_EPILOGUE
#undef RDBAR
#undef WAIT8
#undef WAIT0
}

extern "C" void kernel_launch(void* const* d_in, const int* in_sizes, int n_in,
                              void* d_out, int out_size, void* d_ws, size_t ws_size,
                              hipStream_t stream) {
    const float* za   = (const float*)d_in[0];
    const float* zb   = (const float*)d_in[1];
    const float* bias = (const float*)d_in[2];

    unsigned char* wa = (unsigned char*)d_ws;
    unsigned char* wb = wa + (size_t)Nn * Dd;

    // zero the output accumulator (harness does not re-poison between replays)
    hipMemsetAsync(d_out, 0, sizeof(float), stream);

    // fp32 -> fp8 pre-pass (A pre-scaled by log2e)
    cvt_kernel<<<dim3(Nn * Dd / 2048), 256, 0, stream>>>(
        (const float4*)za, (const float4*)zb, (int2*)wa, (int2*)wb);

    // fused GEMM + loss: 64 M-tiles x 16 N-supertiles = 1024 blocks, 256 thr
    siglip_kernel<<<dim3(1024), 256, 0, stream>>>(wa, wb, bias, (float*)d_out);
}

// Round 20
// 130.596 us; speedup vs baseline: 8.6269x; 8.6269x over previous
//
#include <hip/hip_runtime.h>
#include <hip/hip_bf16.h>

#define Nn 16384
#define Dd 256
#define L2E 1.4426950408889634f
#define LN2 0.6931471805599453f

typedef __attribute__((ext_vector_type(8))) int int8v;
typedef __attribute__((ext_vector_type(16))) float f32x16;
typedef __attribute__((ext_vector_type(2))) float f32x2;

__device__ inline void gload_lds16(const void* g, void* l) {
    __builtin_amdgcn_global_load_lds(
        (const __attribute__((address_space(1))) void*)g,
        (__attribute__((address_space(3))) void*)l, 16, 0, 0);
}

// fp32 -> fp8 e4m3 (HW RNE). A pre-scaled by log2e: epilogue softplus works in
// exp2/log2 domain with no per-element muls.
__global__ __launch_bounds__(256) void cvt_kernel(
        const float4* __restrict__ a, const float4* __restrict__ b,
        int2* __restrict__ oa, int2* __restrict__ ob) {
    int i = blockIdx.x * 256 + threadIdx.x;
    float4 a0 = a[2 * i], a1 = a[2 * i + 1];
    float4 b0 = b[2 * i], b1 = b[2 * i + 1];
    int alo = __builtin_amdgcn_cvt_pk_fp8_f32(a0.x * L2E, a0.y * L2E, 0, false);
    alo     = __builtin_amdgcn_cvt_pk_fp8_f32(a0.z * L2E, a0.w * L2E, alo, true);
    int ahi = __builtin_amdgcn_cvt_pk_fp8_f32(a1.x * L2E, a1.y * L2E, 0, false);
    ahi     = __builtin_amdgcn_cvt_pk_fp8_f32(a1.z * L2E, a1.w * L2E, ahi, true);
    int blo = __builtin_amdgcn_cvt_pk_fp8_f32(b0.x, b0.y, 0, false);
    blo     = __builtin_amdgcn_cvt_pk_fp8_f32(b0.z, b0.w, blo, true);
    int bhi = __builtin_amdgcn_cvt_pk_fp8_f32(b1.x, b1.y, 0, false);
    bhi     = __builtin_amdgcn_cvt_pk_fp8_f32(b1.z, b1.w, bhi, true);
    oa[i] = make_int2(alo, ahi);
    ob[i] = make_int2(blo, bhi);
}

// 2x ds_read_b128 of one lane's 32 contiguous K-bytes from a [rows][256B]
// full-K LDS tile, XOR-deswizzled (16 chunks/row, chunk ^= row&15).
// Measured ZERO bank conflicts (R8-R18). LDS dest LINEAR (rule #21);
// swizzle lives on the global SOURCE side only.
__device__ inline int8v read_frag256(const unsigned char* base, int rr, int cb) {
    int x = rr & 15;
    int4 lo = *(const int4*)&base[rr * 256 + ((cb ^ x) * 16)];
    int4 hi = *(const int4*)&base[rr * 256 + (((cb + 1) ^ x) * 16)];
    int8v r;
    r[0] = lo.x; r[1] = lo.y; r[2] = lo.z; r[3] = lo.w;
    r[4] = hi.x; r[5] = hi.y; r[6] = hi.z; r[7] = hi.w;
    return r;
}

// Fused MX-fp8 GEMM (sim' = log2e * za.zb^T, unit e8m0 scales) + siglip loss.
// R18 terminal structure: persistent-A pipelined-B, 256 thr = 4 waves =
// 1 wave/SIMD, __launch_bounds__(256,1). SPILL LAW (R3/4/8/9/12/13/14/19):
// exactly ONE live acc generation — arch-VGPR hard-caps at 256 and every
// 2-generation variant spilled regardless of fences/pins/occupancy. Block =
// 256 M-rows x 1024 N-cols (8 panels of 128). A[256][256B] staged once
// (64KB); B double-buffered (2x32KB), 2 panels ahead, counted vmcnt(8);
// vmcnt(0) only at the last panel. Per-panel epilogue (single-acc, runs
// between stage-issue and wait -> overlaps B-flight) in the cheap form:
// loss/elem ~= ln2*m + 2^(y-2m), m=max(y,0)  [y-2m == -|y|; e^2/2 dropped,
// absmax 0.031 proven R10-R18]. VGPR=252, WRITE=32B at R18.
__global__ __launch_bounds__(256, 1) void siglip_kernel(
        const unsigned char* __restrict__ ga,   // za*log2e fp8 [16384][256]
        const unsigned char* __restrict__ gb,   // zb fp8 [16384][256]
        const float* __restrict__ bp,           // bias scalar
        float* __restrict__ out) {
    __shared__ unsigned char As[256 * 256];    // 64 KB, full-K A tile
    __shared__ unsigned char Bs0[128 * 256];   // 32 KB, B panel buffer 0
    __shared__ unsigned char Bs1[128 * 256];   // 32 KB, B panel buffer 1
    __shared__ float wsum[4];

    const int tid  = threadIdx.x;
    const int lane = tid & 63;
    const int wid  = tid >> 6;     // 0..3
    const int wm   = wid;          // 64-row slice of the 256-row tile
    const int l31  = lane & 31;
    const int h    = lane >> 5;

    // XCD-chunked bijective swizzle (grid 1024 = 8 XCD x 128); consecutive
    // nid share the A panel (same by) and sweep B -> per-XCD L2 locality.
    const int bid = blockIdx.x;
    const int nid = (bid & 7) * 128 + (bid >> 3);
    const int by  = nid >> 4;      // 0..63  M-tile (256 rows)
    const int bxs = nid & 15;      // 0..15  N-supertile (1024 cols)
    const size_t rowA0 = (size_t)by * 256;
    const int    rB0   = bxs * 1024;

    const float b2 = bp[0] * L2E;

    // ---- stage A once: 16 loads/thread; LDS dest linear, source swizzled ----
#pragma unroll
    for (int p = 0; p < 16; ++p) {
        int c = p * 256 + tid; int row = c >> 4;
        int scl = (c & 15) ^ (row & 15);
        gload_lds16(&ga[(rowA0 + row) * Dd + scl * 16], &As[c * 16]);
    }

#define STAGE_B(DST, T)                                                       \
    {                                                                         \
        _Pragma("unroll")                                                     \
        for (int p = 0; p < 8; ++p) {                                         \
            int c = p * 256 + tid; int row = c >> 4;                          \
            int scl = (c & 15) ^ (row & 15);                                  \
            gload_lds16(&gb[(size_t)(rB0 + (T) * 128 + row) * Dd + scl * 16], \
                        &(DST)[c * 16]);                                      \
        }                                                                     \
    }

    STAGE_B(Bs0, 0)
    STAGE_B(Bs1, 1)

    // outstanding: A(16)+B0(8)+B1(8)=32; wait to <=8 -> A and B0 landed.
    asm volatile("s_waitcnt vmcnt(8)" ::: "memory");
    __builtin_amdgcn_s_barrier();
    asm volatile("" ::: "memory");

    f32x2 sm = {0.f, 0.f}, se = {0.f, 0.f};
    float ld = 0.f;
    const int diagblk = (bxs == (by >> 2));
    const int dtile   = (by & 3);

#pragma unroll 1
    for (int t = 0; t < 8; ++t) {
        const unsigned char* Bb = (t & 1) ? Bs1 : Bs0;
        unsigned char*       Bw = (t & 1) ? Bs1 : Bs0;

        f32x16 acc[2][4];
#pragma unroll
        for (int mf = 0; mf < 2; ++mf)
#pragma unroll
            for (int nf = 0; nf < 4; ++nf)
#pragma unroll
                for (int q = 0; q < 16; ++q) acc[mf][nf][q] = -b2;

        // ---- 4 s-steps of K=64B: 6 ds_reads + 8 MFMAs each ----
#pragma unroll
        for (int s = 0; s < 4; ++s) {
            int cb = s * 4 + h * 2;
            int8v aF0 = read_frag256(As, wm * 64 + l31, cb);
            int8v aF1 = read_frag256(As, wm * 64 + 32 + l31, cb);
#pragma unroll
            for (int nf = 0; nf < 4; ++nf) {
                int8v bF = read_frag256(Bb, nf * 32 + l31, cb);
                acc[0][nf] = __builtin_amdgcn_mfma_scale_f32_32x32x64_f8f6f4(
                    aF0, bF, acc[0][nf], 0, 0, 0, 0x7F7F7F7F, 0, 0x7F7F7F7F);
                acc[1][nf] = __builtin_amdgcn_mfma_scale_f32_32x32x64_f8f6f4(
                    aF1, bF, acc[1][nf], 0, 0, 0, 0x7F7F7F7F, 0, 0x7F7F7F7F);
            }
        }

        // all waves done reading this buffer -> safe to re-stage it
        asm volatile("" ::: "memory");
        __builtin_amdgcn_s_barrier();
        asm volatile("" ::: "memory");
        if (t < 6) STAGE_B(Bw, t + 2)

        // ---- per-panel epilogue (packed, cheap form; overlaps B-flight) ----
        // loss/elem(nats) ~= ln2*m + 2^(y-2m), m=max(y,0); y-2m == -|y|.
#pragma unroll
        for (int mf = 0; mf < 2; ++mf)
#pragma unroll
            for (int nf = 0; nf < 4; ++nf)
#pragma unroll
                for (int q = 0; q < 16; q += 2) {
                    f32x2 yv = {acc[mf][nf][q], acc[mf][nf][q + 1]};
                    f32x2 mv = {fmaxf(yv[0], 0.f), fmaxf(yv[1], 0.f)};
                    f32x2 tv = yv - 2.f * mv;      // v_pk_fma -> -|y|
                    sm += mv;                      // v_pk_add_f32
                    f32x2 ev = {__builtin_amdgcn_exp2f(tv[0]),
                                __builtin_amdgcn_exp2f(tv[1])};
                    se += ev;                      // v_pk_add_f32
                }

        // diagonal correction: only on the 2 panels meeting this row-range
        if (diagblk && (t >> 1) == dtile) {
#pragma unroll
            for (int mf = 0; mf < 2; ++mf)
#pragma unroll
                for (int nf = 0; nf < 4; ++nf)
#pragma unroll
                    for (int q = 0; q < 16; ++q) {
                        int i_loc = wm * 64 + mf * 32 + (q & 3) + 8 * (q >> 2) + 4 * h;
                        int jg    = ((t & 1) << 7) + nf * 32 + l31;
                        if (i_loc == jg) {
                            float y  = acc[mf][nf][q];
                            float u  = -(y + 2.f * b2);
                            float ey = __builtin_amdgcn_exp2f(-fabsf(y));
                            float eu = __builtin_amdgcn_exp2f(-fabsf(u));
                            float off = LN2 * fmaxf(y, 0.f) + ey;
                            float dg  = LN2 * fmaxf(u, 0.f) + eu;
                            ld += dg - off;
                        }
                    }
        }

        if (t < 6) {
            asm volatile("s_waitcnt vmcnt(8)" ::: "memory");  // B(t+1) landed
            __builtin_amdgcn_s_barrier();
            asm volatile("" ::: "memory");
        } else if (t == 6) {
            asm volatile("s_waitcnt vmcnt(0)" ::: "memory");  // B7 landed
            __builtin_amdgcn_s_barrier();
            asm volatile("" ::: "memory");
        }
    }

    // v = ln2*Σm + Σe + diag
    float v = fmaf(LN2, sm[0] + sm[1], se[0] + se[1] + ld);

    // wave reduce then block reduce
#pragma unroll
    for (int off = 32; off; off >>= 1)
        v += __shfl_down(v, off);
    if (lane == 0) wsum[wid] = v;
    __syncthreads();
    if (tid == 0) {
        float t = wsum[0] + wsum[1] + wsum[2] + wsum[3];
        atomicAdd(out, t * (1.0f / ((float)Nn * (float)Nn)));
    }
#undef STAGE_B
}

extern "C" void kernel_launch(void* const* d_in, const int* in_sizes, int n_in,
                              void* d_out, int out_size, void* d_ws, size_t ws_size,
                              hipStream_t stream) {
    const float* za   = (const float*)d_in[0];
    const float* zb   = (const float*)d_in[1];
    const float* bias = (const float*)d_in[2];

    unsigned char* wa = (unsigned char*)d_ws;
    unsigned char* wb = wa + (size_t)Nn * Dd;

    // zero the output accumulator (harness does not re-poison between replays)
    hipMemsetAsync(d_out, 0, sizeof(float), stream);

    // fp32 -> fp8 pre-pass (A pre-scaled by log2e)
    cvt_kernel<<<dim3(Nn * Dd / 2048), 256, 0, stream>>>(
        (const float4*)za, (const float4*)zb, (int2*)wa, (int2*)wb);

    // fused GEMM + loss: 64 M-tiles x 16 N-supertiles = 1024 blocks, 256 thr
    siglip_kernel<<<dim3(1024), 256, 0, stream>>>(wa, wb, bias, (float*)d_out);
}